// Round 2
// baseline (445.234 us; speedup 1.0000x reference)
//
#include <hip/hip_runtime.h>
#include <hip/hip_bf16.h>
#include <stdint.h>

#define NIMG   32
#define CCH    256
#define WD     56
#define HW     3136         // 56*56
#define STRIPS 28           // 56 / 2 rows per block
#define KCTOT  36           // 4 ci-chunks * 9 taps

typedef __attribute__((ext_vector_type(8))) short    bf16x8;
typedef __attribute__((ext_vector_type(4))) float    f32x4;
typedef __attribute__((ext_vector_type(4))) uint32_t u32x4;

typedef __attribute__((address_space(1))) const uint8_t* as1cp;
typedef __attribute__((address_space(3))) uint8_t*       as3p;

static __device__ __forceinline__ uint16_t f2bf(float f) {
  uint32_t b = __float_as_uint(f);
  return (uint16_t)((b + 0x7fffu + ((b >> 16) & 1u)) >> 16);   // RN-even
}

// ---------- prepass 1: dequantize weights -> bf16, layout [co][kc=cc*9+tap][64 ci] ----------
__global__ __launch_bounds__(256) void dequant_weights(
    const int* __restrict__ widx, const float* __restrict__ lut,
    uint16_t* __restrict__ Bw) {
  int idx = blockIdx.x * 256 + threadIdx.x;        // < 589824
  int co  = idx / (KCTOT * 64);
  int r   = idx - co * (KCTOT * 64);
  int kc  = r >> 6;
  int cil = r & 63;
  int cc  = kc / 9;
  int tap = kc - cc * 9;
  int ci  = cc * 64 + cil;
  Bw[idx] = f2bf(lut[widx[(co * CCH + ci) * 9 + tap]]);
}

// ---------- prepass 2: NCHW fp32 -> NHWC bf16 ----------
__global__ __launch_bounds__(256) void transpose_in(
    const float* __restrict__ in, uint16_t* __restrict__ outT) {
  const int t    = threadIdx.x;
  const int ci_l = t & 63;
  const int s4_l = t >> 6;
  const int n    = blockIdx.z;
  const int cic  = blockIdx.y;
  const int s4   = blockIdx.x * 4 + s4_l;          // 0..783
  const int ci   = cic * 64 + ci_l;
  const float4 v = *(const float4*)(in + ((size_t)(n * CCH + ci)) * HW + s4 * 4);
  uint16_t* ob = outT + ((size_t)n * HW + (size_t)s4 * 4) * CCH + ci;
  ob[0]   = f2bf(v.x);
  ob[256] = f2bf(v.y);
  ob[512] = f2bf(v.z);
  ob[768] = f2bf(v.w);
}

// ---------- main: halo-tile implicit-GEMM conv ----------
__global__ __launch_bounds__(256) void conv_mfma(
    const uint16_t* __restrict__ inT, const uint16_t* __restrict__ Bw,
    const float* __restrict__ bias, float* __restrict__ out) {

  // A halo tile: 4 h-rows x 64 w-slots x 64 ci bf16 = 32 KB.
  // Pixel slot p = hr*64 + wr (wr = w+1; wr 0 and 57 are zero pads).
  // Slot granule gs holds GLOBAL granule gs ^ (p&7)  (conflict-free frag reads).
  __shared__ __align__(16) uint8_t A_lds[4 * 64 * 128];

  const int t    = threadIdx.x;
  const int lane = t & 63;
  const int wv   = t >> 6;
  const int wm   = wv & 1;          // h-row within strip
  const int wn   = wv >> 1;         // co 64-half
  const int lrow = lane & 15;
  const int kgrp = lane >> 4;

  const int bx    = blockIdx.x;              // 0..895
  const int n     = bx / STRIPS;
  const int strip = bx - n * STRIPS;
  const int h0    = strip * 2;
  const int co0   = blockIdx.y * 128;

  // ---- B row pointers (global, L2-resident) + first prefetch ----
  const uint16_t* bni[4];
#pragma unroll
  for (int ni = 0; ni < 4; ++ni)
    bni[ni] = Bw + ((size_t)(co0 + wn * 64 + ni * 16 + lrow)) * (KCTOT * 64) + kgrp * 8;

  bf16x8 bfr[2][8];
#pragma unroll
  for (int ks = 0; ks < 2; ++ks)
#pragma unroll
    for (int ni = 0; ni < 4; ++ni)
      bfr[0][ks * 4 + ni] = *(const bf16x8*)(bni[ni] + 0 * 64 + ks * 32);

  // ---- staging lane constants ----
  const int pg       = ((lane >> 3) + 1) & 7;          // (p & 7) for this lane's pixel
  const int perm     = (lane & 7) ^ pg;                // global granule this lane fetches
  const size_t lsoff = (size_t)(lane >> 3) * 512 + (size_t)perm * 16;  // bytes
  const int hr_s     = wv;                             // each wave stages one h-row
  const int h_s      = h0 - 1 + hr_s;
  const bool row_valid = (unsigned)h_s < 56u;

  // ---- one-time zero fills (pads + invalid halo rows) ----
  {
    const u32x4 z = (u32x4){0u, 0u, 0u, 0u};
    if (wv == 0) {   // 8 pad slots: (hr, wr=0) and (hr, wr=57)
      int sl = lane >> 3;
      int hr = sl >> 1;
      int wr = (sl & 1) ? 57 : 0;
      *(u32x4*)(A_lds + (hr * 64 + wr) * 128 + (lane & 7) * 16) = z;
    }
    if (!row_valid) {
#pragma unroll
      for (int j = 0; j < 7; ++j)
        *(u32x4*)(A_lds + (hr_s * 64 + 1 + j * 8) * 128 + lane * 16) = z;
    }
  }

  // ---- acc init ----
  f32x4 acc[4][4];
#pragma unroll
  for (int i = 0; i < 4; ++i)
#pragma unroll
    for (int j = 0; j < 4; ++j)
      acc[i][j] = (f32x4){0.f, 0.f, 0.f, 0.f};

  // A fragment w-index (clamped; lanes with w>=56 are dead, never stored)
  int pw[4];
#pragma unroll
  for (int mi = 0; mi < 4; ++mi) {
    int w = mi * 16 + lrow;
    pw[mi] = (w > 55 ? 55 : w) + 1;
  }

  const uint8_t* g_row = (const uint8_t*)(inT + ((size_t)n * HW + (size_t)h_s * WD) * CCH);

#pragma unroll 1
  for (int cc = 0; cc < 4; ++cc) {
    // ---- stage A halo tile for this ci-chunk (each wave: its h-row, 7x 1KB) ----
    if (row_valid) {
      const uint8_t* gbase = g_row + (size_t)cc * 128;   // + cc*64 ci * 2B
#pragma unroll
      for (int j = 0; j < 7; ++j) {
        uint8_t* ldst = A_lds + (hr_s * 64 + 1 + j * 8) * 128;   // wave-uniform
        __builtin_amdgcn_global_load_lds((as1cp)(gbase + (size_t)j * 8 * 512 + lsoff),
                                         (as3p)ldst, 16, 0, 0);
      }
    }
    __syncthreads();

    // ---- 9 taps, all from the resident tile; B ping-pong prefetch ----
#pragma unroll
    for (int tap = 0; tap < 9; ++tap) {
      const int kc  = cc * 9 + tap;
      const int cur = tap & 1;
      if (kc < 35) {
#pragma unroll
        for (int ks = 0; ks < 2; ++ks)
#pragma unroll
          for (int ni = 0; ni < 4; ++ni)
            bfr[cur ^ 1][ks * 4 + ni] =
                *(const bf16x8*)(bni[ni] + (size_t)(kc + 1) * 64 + ks * 32);
      }
      const int dh = tap / 3 - 1;
      const int dw = tap % 3 - 1;
      const int prow = (wm + dh + 1) * 64;

#pragma unroll
      for (int ks = 0; ks < 2; ++ks) {
        bf16x8 af[4];
#pragma unroll
        for (int mi = 0; mi < 4; ++mi) {
          const int p  = prow + pw[mi] + dw;
          const int gs = (ks * 4 + kgrp) ^ (p & 7);
          af[mi] = *(const bf16x8*)(A_lds + p * 128 + gs * 16);
        }
#pragma unroll
        for (int mi = 0; mi < 4; ++mi)
#pragma unroll
          for (int ni = 0; ni < 4; ++ni)
            acc[mi][ni] = __builtin_amdgcn_mfma_f32_16x16x32_bf16(
                af[mi], bfr[cur][ks * 4 + ni], acc[mi][ni], 0, 0, 0);
      }
    }

    // roll prefetched next-cc B into buffer 0 (tap=8 used buf 0, loaded buf 1)
#pragma unroll
    for (int i = 0; i < 8; ++i) bfr[0][i] = bfr[1][i];

    __syncthreads();   // protect tile before next cc overwrites
  }

  // ---- epilogue: bias + per-wave LDS transpose -> vectorized w-stores ----
  float bv[4];
#pragma unroll
  for (int ni = 0; ni < 4; ++ni)
    bv[ni] = bias[co0 + wn * 64 + ni * 16 + lrow];

  uint8_t* scr = A_lds + wv * 5120;            // 64 co x 20 floats (16 w + pad)
  const int h_out = h0 + wm;
  float* obase = out + ((size_t)(n * CCH + co0 + wn * 64)) * HW + h_out * WD;

#pragma unroll
  for (int mi = 0; mi < 4; ++mi) {
#pragma unroll
    for (int ni = 0; ni < 4; ++ni) {
      f32x4 vv = acc[mi][ni];
      vv[0] += bv[ni]; vv[1] += bv[ni]; vv[2] += bv[ni]; vv[3] += bv[ni];
      *(f32x4*)(scr + (ni * 16 + lrow) * 80 + kgrp * 16) = vv;   // [co][w16]
    }
    const int jmax = (mi == 3) ? 2 : 4;        // mi=3: only w 48..55 valid
    for (int j = 0; j < jmax; ++j) {
      f32x4 vv = *(const f32x4*)(scr + lane * 80 + j * 16);
      *(f32x4*)(obase + (size_t)lane * HW + mi * 16 + j * 4) = vv;
    }
  }
}

extern "C" void kernel_launch(void* const* d_in, const int* in_sizes, int n_in,
                              void* d_out, int out_size, void* d_ws, size_t ws_size,
                              hipStream_t stream) {
  const float* in   = (const float*)d_in[0];
  const int*   widx = (const int*)d_in[1];
  const float* lut  = (const float*)d_in[2];
  const float* bias = (const float*)d_in[3];
  float* out = (float*)d_out;

  uint16_t* Bw  = (uint16_t*)d_ws;                            // 1.18 MB
  uint16_t* inT = (uint16_t*)((char*)d_ws + (2u << 20));      // 51.4 MB NHWC bf16

  dequant_weights<<<dim3(589824 / 256), dim3(256), 0, stream>>>(widx, lut, Bw);
  transpose_in<<<dim3(196, 4, NIMG), dim3(256), 0, stream>>>(in, inT);
  conv_mfma<<<dim3(NIMG * STRIPS, 2), dim3(256), 0, stream>>>(inT, Bw, bias, out);
}